// Round 1
// baseline (692.487 us; speedup 1.0000x reference)
//
#include <hip/hip_runtime.h>
#include <math.h>

#define N 128
#define LOGN 7
#define VOL (N*N*N)            // 2097152
#define NSHELL 65              // shells 0..64
#define ACC_STRIDE 195         // 3*65 per batch

__device__ __forceinline__ int rev7(int x) {
    return (int)(__brev((unsigned)x) >> 25);
}

__device__ __forceinline__ void init_tw(float2* tw, int tid) {
    if (tid < 64) {
        float ang = -6.283185307179586f * (float)tid / 128.0f;
        tw[tid] = make_float2(cosf(ang), sinf(ang));
    }
}

// one radix-2 DIT stage on a column of 128 float2 (stride-1 in LDS), 64 lanes
__device__ __forceinline__ void butterfly_stage(float2* col, const float2* tw,
                                                int lane, int s) {
    int half = 1 << (s - 1);
    int grp  = lane >> (s - 1);
    int pos  = lane & (half - 1);
    int i0   = (grp << s) + pos;
    int i1   = i0 + half;
    float2 w = tw[pos << (LOGN - s)];
    float2 a = col[i0];
    float2 b = col[i1];
    float tr = w.x * b.x - w.y * b.y;
    float ti = w.x * b.y + w.y * b.x;
    col[i0] = make_float2(a.x + tr, a.y + ti);
    col[i1] = make_float2(a.x - tr, a.y - ti);
}

// ---------------- Pass 1: FFT along x (contiguous), real->complex ----------
// grid: nb*8192 blocks of 256 (4 waves, 1 line per wave)
__global__ __launch_bounds__(256)
void fft_x_kernel(const float* __restrict__ in0, const float* __restrict__ in1,
                  float2* __restrict__ wsv, int nb, int b0, float scale)
{
    __shared__ float2 ldata[4][N];
    __shared__ float2 tw[64];
    int tid  = threadIdx.x;
    int wave = tid >> 6;
    int lane = tid & 63;
    init_tw(tw, tid);

    int line = blockIdx.x * 4 + wave;       // 0 .. 2*nb*16384-1
    int vol  = line >> 14;                  // 0 .. 2nb-1
    int rem  = line & 16383;                // (z*128 + y)
    const float* src = (vol < nb)
        ? in0 + (size_t)(b0 + vol) * VOL
        : in1 + (size_t)(b0 + vol - nb) * VOL;
    src += (size_t)rem * N;

    ldata[wave][rev7(lane)]      = make_float2(src[lane]      * scale, 0.0f);
    ldata[wave][rev7(lane + 64)] = make_float2(src[lane + 64] * scale, 0.0f);
    __syncthreads();

    #pragma unroll
    for (int s = 1; s <= LOGN; s++) {
        butterfly_stage(ldata[wave], tw, lane, s);
        __syncthreads();
    }

    float2* dst = wsv + (size_t)vol * VOL + (size_t)rem * N;
    dst[lane]      = ldata[wave][lane];
    dst[lane + 64] = ldata[wave][lane + 64];
}

// ---------------- Pass 2: FFT along y (stride 128), in-place ---------------
// grid: 2*nb*1024 blocks of 256; block = tile of 16 x-columns at fixed (vol,z)
__global__ __launch_bounds__(256)
void fft_y_kernel(float2* __restrict__ wsv)
{
    __shared__ float2 tile[16][129];
    __shared__ float2 tw[64];
    int tid = threadIdx.x;
    int bi  = blockIdx.x;
    int xt  = bi & 7;
    int z   = (bi >> 3) & 127;
    int vol = bi >> 10;
    size_t base = (size_t)vol * VOL + (size_t)z * (N * N) + (size_t)xt * 16;
    init_tw(tw, tid);

    #pragma unroll
    for (int e = 0; e < 8; e++) {
        int idx = tid + 256 * e;
        int y = idx >> 4, xl = idx & 15;
        tile[xl][rev7(y)] = wsv[base + (size_t)y * N + xl];
    }
    __syncthreads();

    int lane = tid & 63, wave = tid >> 6;
    #pragma unroll
    for (int s = 1; s <= LOGN; s++) {
        #pragma unroll
        for (int c = 0; c < 4; c++) {
            butterfly_stage(tile[(wave << 2) + c], tw, lane, s);
        }
        __syncthreads();
    }

    #pragma unroll
    for (int e = 0; e < 8; e++) {
        int idx = tid + 256 * e;
        int y = idx >> 4, xl = idx & 15;
        wsv[base + (size_t)y * N + xl] = tile[xl][y];
    }
}

// -------- Pass 3: FFT along z (stride 16384) + fused shell accumulation ----
// grid: nb*1024 blocks of 256; block = tile of 16 x at fixed (batch, y)
__global__ __launch_bounds__(256)
void fft_z_acc_kernel(const float2* __restrict__ wsv, float* __restrict__ gacc,
                      int nb, int b0)
{
    __shared__ float2 to[16][129];
    __shared__ float2 tt[16][129];
    __shared__ float2 tw[64];
    __shared__ float accn[NSHELL], accp[NSHELL], accq[NSHELL];
    int tid = threadIdx.x;
    int bi  = blockIdx.x;
    int xt  = bi & 7;
    int y   = (bi >> 3) & 127;
    int b   = bi >> 10;
    size_t baseo = (size_t)b * VOL        + (size_t)y * N + (size_t)xt * 16;
    size_t baset = (size_t)(b + nb) * VOL + (size_t)y * N + (size_t)xt * 16;
    init_tw(tw, tid);
    if (tid < NSHELL) { accn[tid] = 0.0f; accp[tid] = 0.0f; accq[tid] = 0.0f; }

    #pragma unroll
    for (int e = 0; e < 8; e++) {
        int idx = tid + 256 * e;
        int z = idx >> 4, xl = idx & 15;
        int zr = rev7(z);
        to[xl][zr] = wsv[baseo + (size_t)z * (N * N) + xl];
        tt[xl][zr] = wsv[baset + (size_t)z * (N * N) + xl];
    }
    __syncthreads();

    int lane = tid & 63, wave = tid >> 6;
    #pragma unroll
    for (int s = 1; s <= LOGN; s++) {
        #pragma unroll
        for (int c = 0; c < 4; c++) {
            int col = (wave << 2) + c;
            butterfly_stage(to[col], tw, lane, s);
            butterfly_stage(tt[col], tw, lane, s);
        }
        __syncthreads();
    }

    int cy = (y < 64) ? y : y - 128;
    #pragma unroll
    for (int e = 0; e < 8; e++) {
        int idx = tid + 256 * e;
        int z = idx >> 4, xl = idx & 15;
        int cz = (z < 64) ? z : z - 128;
        int x  = (xt << 4) + xl;
        int cx = (x < 64) ? x : x - 128;
        int r2 = cz * cz + cy * cy + cx * cx;
        int sh = (int)sqrtf((float)r2);
        if (sh <= 64) {
            float2 o = to[xl][z];
            float2 t = tt[xl][z];
            atomicAdd(&accn[sh], o.x * t.x + o.y * t.y);
            atomicAdd(&accp[sh], o.x * o.x + o.y * o.y);
            atomicAdd(&accq[sh], t.x * t.x + t.y * t.y);
        }
    }
    __syncthreads();

    if (tid < NSHELL) {
        float* g = gacc + (size_t)(b0 + b) * ACC_STRIDE;
        atomicAdd(&g[tid],            accn[tid]);
        atomicAdd(&g[NSHELL + tid],   accp[tid]);
        atomicAdd(&g[2*NSHELL + tid], accq[tid]);
    }
}

// ---------------- Finalize: fsc -> loss scalar -----------------------------
__global__ void finalize_kernel(const float* __restrict__ gacc,
                                float* __restrict__ out)
{
    int lane = threadIdx.x;   // 64 threads, shell = lane+1 (1..64)
    int sh = lane + 1;
    float total = 0.0f;
    #pragma unroll
    for (int b = 0; b < 8; b++) {
        const float* g = gacc + b * ACC_STRIDE;
        float num = g[sh];
        float po  = g[NSHELL + sh];
        float pt  = g[2*NSHELL + sh];
        float fsc = num / sqrtf(po * pt + 1e-6f);
        fsc = fminf(1.0f, fmaxf(-1.0f, fsc));
        total += fsc;
    }
    #pragma unroll
    for (int off = 32; off; off >>= 1) total += __shfl_down(total, off);
    if (lane == 0) out[0] = 1.0f - total / (64.0f * 8.0f);
}

extern "C" void kernel_launch(void* const* d_in, const int* in_sizes, int n_in,
                              void* d_out, int out_size, void* d_ws, size_t ws_size,
                              hipStream_t stream) {
    const float* in0 = (const float*)d_in[0];   // model_output (8,1,128,128,128)
    const float* in1 = (const float*)d_in[1];   // target
    float* gacc  = (float*)d_ws;                               // 8*195 floats
    float2* wsv  = (float2*)((char*)d_ws + 8192);              // complex volumes

    hipMemsetAsync(d_ws, 0, 8 * ACC_STRIDE * sizeof(float), stream);

    size_t avail = (ws_size > 8192) ? ws_size - 8192 : 0;
    size_t per_batch = 2ull * VOL * sizeof(float2);            // 33.5 MB
    int NB = (int)(avail / per_batch);
    if (NB > 8) NB = 8;
    if (NB < 1) NB = 1;

    const float scale = 6.905339660024879e-4f;  // 1/sqrt(128^3)

    for (int b0 = 0; b0 < 8; b0 += NB) {
        int nb = (8 - b0 < NB) ? (8 - b0) : NB;
        fft_x_kernel<<<dim3(nb * 8192), dim3(256), 0, stream>>>(in0, in1, wsv, nb, b0, scale);
        fft_y_kernel<<<dim3(2 * nb * 1024), dim3(256), 0, stream>>>(wsv);
        fft_z_acc_kernel<<<dim3(nb * 1024), dim3(256), 0, stream>>>(wsv, gacc, nb, b0);
    }
    finalize_kernel<<<dim3(1), dim3(64), 0, stream>>>(gacc, (float*)d_out);
}

// Round 2
// 404.292 us; speedup vs baseline: 1.7128x; 1.7128x over previous
//
#include <hip/hip_runtime.h>
#include <math.h>

#define N 128
#define LOGN 7
#define VOL (N*N*N)            // 2097152
#define PLANE (N*N)            // 16384
#define NKX 65                 // kept x-frequencies 0..64 (Hermitian half)
#define NSHELL 65              // shells 0..64
#define ACC_STRIDE 195         // 3*65 per batch

__device__ __forceinline__ int rev7(int x) {
    return (int)(__brev((unsigned)x) >> 25);
}

__device__ __forceinline__ void init_tw(float2* tw, int tid) {
    if (tid < 64) {
        float ang = -6.283185307179586f * (float)tid / 128.0f;
        tw[tid] = make_float2(cosf(ang), sinf(ang));
    }
}

// one radix-2 DIT stage on a column of 128 float2 (stride-1 in LDS), 64 lanes
__device__ __forceinline__ void butterfly_stage(float2* col, const float2* tw,
                                                int lane, int s) {
    int half = 1 << (s - 1);
    int grp  = lane >> (s - 1);
    int pos  = lane & (half - 1);
    int i0   = (grp << s) + pos;
    int i1   = i0 + half;
    float2 w = tw[pos << (LOGN - s)];
    float2 a = col[i0];
    float2 b = col[i1];
    float tr = w.x * b.x - w.y * b.y;
    float ti = w.x * b.y + w.y * b.x;
    col[i0] = make_float2(a.x + tr, a.y + ti);
    col[i1] = make_float2(a.x - tr, a.y - ti);
}

// split re/im butterfly (conflict-free: b32 accesses, i0 distinct mod 32 -> 2-way)
__device__ __forceinline__ void butterfly_split(float* re, float* im,
                                                const float* twr, const float* twi,
                                                int lane, int s) {
    int half = 1 << (s - 1);
    int pos  = lane & (half - 1);
    int i0   = ((lane >> (s - 1)) << s) + pos;
    int i1   = i0 + half;
    float wr = twr[pos << (LOGN - s)];
    float wi = twi[pos << (LOGN - s)];
    float br = re[i1], bi = im[i1];
    float tr = wr * br - wi * bi;
    float ti = wr * bi + wi * br;
    float ar = re[i0], ai = im[i0];
    re[i0] = ar + tr; im[i0] = ai + ti;
    re[i1] = ar - tr; im[i1] = ai - ti;
}

// ---- Pass 1: packed x-FFT (L = mo + i*tg), Hermitian unpack, keep kx=0..64 ----
// grid: nb*128(z)*8(ytile) blocks of 256. Output layout: [vol][b][kx][z][y].
__global__ __launch_bounds__(256)
void fft_x_pack_kernel(const float* __restrict__ in0, const float* __restrict__ in1,
                       float2* __restrict__ wso, float2* __restrict__ wst,
                       int b0, float scale)
{
    __shared__ float2 tile[16][129];
    __shared__ float2 tw[64];
    int tid = threadIdx.x;
    int bi  = blockIdx.x;
    int yt  = bi & 7;
    int z   = (bi >> 3) & 127;
    int b   = bi >> 10;
    init_tw(tw, tid);

    size_t src_base = (size_t)(b0 + b) * VOL + (size_t)z * PLANE + (size_t)(yt * 16) * N;
    #pragma unroll
    for (int e = 0; e < 8; e++) {
        int idx = tid + 256 * e;
        int x = idx & 127, j = idx >> 7;
        float mv = in0[src_base + (size_t)j * N + x];
        float tv = in1[src_base + (size_t)j * N + x];
        tile[j][rev7(x)] = make_float2(mv * scale, tv * scale);
    }
    __syncthreads();

    int lane = tid & 63, wave = tid >> 6;
    #pragma unroll
    for (int s = 1; s <= LOGN; s++) {
        #pragma unroll
        for (int c = 0; c < 4; c++)
            butterfly_stage(tile[(wave << 2) + c], tw, lane, s);
        __syncthreads();
    }

    // unpack: O = (L(kx)+conj(L(-kx)))/2 ; T = (L(kx)-conj(L(-kx)))/(2i)
    size_t dst_off = (size_t)b * NKX * PLANE + (size_t)z * N + yt * 16;
    for (int idx = tid; idx < 2 * NKX * 16; idx += 256) {
        int j   = idx & 15;
        int c   = idx >> 4;          // 0..129
        int vol = (c >= NKX);
        int kx  = c - vol * NKX;
        float2 a  = tile[j][kx];
        float2 bm = tile[j][(128 - kx) & 127];
        float2 v;
        if (!vol) v = make_float2(0.5f * (a.x + bm.x), 0.5f * (a.y - bm.y));
        else      v = make_float2(0.5f * (a.y + bm.y), 0.5f * (bm.x - a.x));
        float2* dst = vol ? wst : wso;
        dst[dst_off + (size_t)kx * PLANE + j] = v;
    }
}

// ---- Pass 2: y-FFT, lines contiguous (layout [...][z][y]), in-place ----
// grid: nlines/4 blocks of 256; 1 line per wave.
__global__ __launch_bounds__(256)
void fft_y_kernel(float2* __restrict__ ws)
{
    __shared__ float lre[4][128];
    __shared__ float lim[4][128];
    __shared__ float twr[64], twi[64];
    int tid = threadIdx.x, lane = tid & 63, wave = tid >> 6;
    if (tid < 64) {
        float ang = -6.283185307179586f * (float)tid / 128.0f;
        twr[tid] = cosf(ang); twi[tid] = sinf(ang);
    }
    size_t line = (size_t)blockIdx.x * 4 + wave;
    float2* p = ws + line * N;

    float2 a0 = p[lane], a1 = p[lane + 64];
    int r0 = rev7(lane), r1 = rev7(lane + 64);
    lre[wave][r0] = a0.x; lim[wave][r0] = a0.y;
    lre[wave][r1] = a1.x; lim[wave][r1] = a1.y;
    __syncthreads();

    #pragma unroll
    for (int s = 1; s <= LOGN; s++) {
        butterfly_split(lre[wave], lim[wave], twr, twi, lane, s);
        __syncthreads();
    }

    p[lane]      = make_float2(lre[wave][lane],      lim[wave][lane]);
    p[lane + 64] = make_float2(lre[wave][lane + 64], lim[wave][lane + 64]);
}

// ---- Pass 3: z-FFT (stride 128 in plane) + fused weighted shell accumulation ----
// grid: nb*65*8 blocks of 256; block = (batch, kx, ytile of 16)
__global__ __launch_bounds__(256)
void fft_z_acc_kernel(const float2* __restrict__ wso, const float2* __restrict__ wst,
                      float* __restrict__ gacc, int b0)
{
    __shared__ float2 to[16][129];
    __shared__ float2 tt[16][129];
    __shared__ float2 tw[64];
    __shared__ float accn[NSHELL], accp[NSHELL], accq[NSHELL];
    int tid  = threadIdx.x;
    int bi   = blockIdx.x;
    int yt   = bi & 7;
    int rest = bi >> 3;
    int kx   = rest % NKX;
    int b    = rest / NKX;
    init_tw(tw, tid);
    if (tid < NSHELL) { accn[tid] = 0.0f; accp[tid] = 0.0f; accq[tid] = 0.0f; }

    size_t pb = ((size_t)b * NKX + kx) * PLANE + yt * 16;
    #pragma unroll
    for (int e = 0; e < 8; e++) {
        int idx = tid + 256 * e;
        int z = idx >> 4, j = idx & 15;
        int zr = rev7(z);
        to[j][zr] = wso[pb + (size_t)z * N + j];
        tt[j][zr] = wst[pb + (size_t)z * N + j];
    }
    __syncthreads();

    int lane = tid & 63, wave = tid >> 6;
    #pragma unroll
    for (int s = 1; s <= LOGN; s++) {
        #pragma unroll
        for (int c = 0; c < 4; c++) {
            int col = (wave << 2) + c;
            butterfly_stage(to[col], tw, lane, s);
            butterfly_stage(tt[col], tw, lane, s);
        }
        __syncthreads();
    }

    float w   = (kx == 0 || kx == 64) ? 1.0f : 2.0f;  // Hermitian mirror weight
    int   kx2 = kx * kx;
    #pragma unroll
    for (int e = 0; e < 8; e++) {
        int idx = tid + 256 * e;
        int z = idx >> 4, j = idx & 15;
        int y  = yt * 16 + j;
        int cy = (y < 64) ? y : y - 128;
        int cz = (z < 64) ? z : z - 128;
        int r2 = kx2 + cy * cy + cz * cz;
        if (r2 < 4225) {                       // shell <= 64
            int sh = (int)sqrtf((float)r2);
            float2 o = to[j][z];
            float2 t = tt[j][z];
            atomicAdd(&accn[sh], w * (o.x * t.x + o.y * t.y));
            atomicAdd(&accp[sh], w * (o.x * o.x + o.y * o.y));
            atomicAdd(&accq[sh], w * (t.x * t.x + t.y * t.y));
        }
    }
    __syncthreads();

    if (tid < NSHELL) {
        float* g = gacc + (size_t)(b0 + b) * ACC_STRIDE;
        atomicAdd(&g[tid],              accn[tid]);
        atomicAdd(&g[NSHELL + tid],     accp[tid]);
        atomicAdd(&g[2 * NSHELL + tid], accq[tid]);
    }
}

// ---------------- Finalize: fsc -> loss scalar -----------------------------
__global__ void finalize_kernel(const float* __restrict__ gacc,
                                float* __restrict__ out)
{
    int lane = threadIdx.x;   // 64 threads, shell = lane+1 (1..64)
    int sh = lane + 1;
    float total = 0.0f;
    #pragma unroll
    for (int b = 0; b < 8; b++) {
        const float* g = gacc + b * ACC_STRIDE;
        float num = g[sh];
        float po  = g[NSHELL + sh];
        float pt  = g[2 * NSHELL + sh];
        float fsc = num / sqrtf(po * pt + 1e-6f);
        fsc = fminf(1.0f, fmaxf(-1.0f, fsc));
        total += fsc;
    }
    #pragma unroll
    for (int off = 32; off; off >>= 1) total += __shfl_down(total, off);
    if (lane == 0) out[0] = 1.0f - total / (64.0f * 8.0f);
}

extern "C" void kernel_launch(void* const* d_in, const int* in_sizes, int n_in,
                              void* d_out, int out_size, void* d_ws, size_t ws_size,
                              hipStream_t stream) {
    const float* in0 = (const float*)d_in[0];   // model_output (8,1,128,128,128)
    const float* in1 = (const float*)d_in[1];   // target
    float* gacc  = (float*)d_ws;                               // 8*195 floats
    float2* wsv  = (float2*)((char*)d_ws + 8192);

    hipMemsetAsync(d_ws, 0, 8 * ACC_STRIDE * sizeof(float), stream);

    size_t avail = (ws_size > 8192) ? ws_size - 8192 : 0;
    size_t per_batch = 2ull * NKX * PLANE * sizeof(float2);    // ~17 MB
    int NB = (int)(avail / per_batch);
    if (NB > 8) NB = 8;
    if (NB < 1) NB = 1;

    const float scale = 6.905339660024879e-4f;  // 1/sqrt(128^3)

    for (int b0 = 0; b0 < 8; b0 += NB) {
        int nb = (8 - b0 < NB) ? (8 - b0) : NB;
        float2* wso = wsv;
        float2* wst = wsv + (size_t)nb * NKX * PLANE;
        int nlines = 2 * nb * NKX * N;          // both arrays are contiguous
        fft_x_pack_kernel<<<dim3(nb * 1024), dim3(256), 0, stream>>>(in0, in1, wso, wst, b0, scale);
        fft_y_kernel<<<dim3(nlines / 4), dim3(256), 0, stream>>>(wsv);
        fft_z_acc_kernel<<<dim3(nb * NKX * 8), dim3(256), 0, stream>>>(wso, wst, gacc, b0);
    }
    finalize_kernel<<<dim3(1), dim3(64), 0, stream>>>(gacc, (float*)d_out);
}

// Round 3
// 375.243 us; speedup vs baseline: 1.8454x; 1.0774x over previous
//
#include <hip/hip_runtime.h>
#include <math.h>

#define N 128
#define VOL (N*N*N)            // 2097152
#define PLANE (N*N)            // 16384
#define NKX 65                 // kept x-frequencies 0..64 (Hermitian half)
#define NSHELL 65              // shells 0..64
#define ACC_STRIDE 195         // 3*65 per batch

__device__ __forceinline__ int rev6(int x) { return (int)(__brev((unsigned)x) >> 26); }

__device__ __forceinline__ float2 cmul(float2 a, float2 b) {
    return make_float2(a.x * b.x - a.y * b.y, a.x * b.y + a.y * b.x);
}
__device__ __forceinline__ float2 shflx(float2 v, int m) {
    return make_float2(__shfl_xor(v.x, m), __shfl_xor(v.y, m));
}

// Per-lane twiddles for the register-resident 128-pt DIF FFT (computed once,
// reused for every FFT the wave performs).
struct Tw { float2 w128; float2 t[5]; };

__device__ __forceinline__ Tw make_tw(int lane) {
    Tw w; float s, c;
    sincosf(-6.283185307179586f * (float)lane / 128.0f, &s, &c);
    w.w128 = make_float2(c, s);
    #pragma unroll
    for (int i = 0; i < 5; i++) {
        int h = 32 >> i;                       // 32,16,8,4,2 ; radix block m=2h
        int j = lane & (h - 1);
        sincosf(-6.283185307179586f * (float)j / (float)(2 * h), &s, &c);
        w.t[i] = make_float2(c, s);
    }
    return w;
}

// 128-pt DIF FFT, wave-resident: lane holds x[lane] (v0) and x[lane+64] (v1).
// Output: v0 = X[2*rev6(lane)], v1 = X[2*rev6(lane)+1]  (bit-reversed slots).
__device__ __forceinline__ void fft128(float2& v0, float2& v1, const Tw& w, int lane) {
    float2 d = make_float2(v0.x - v1.x, v0.y - v1.y);
    v0 = make_float2(v0.x + v1.x, v0.y + v1.y);
    v1 = cmul(d, w.w128);
    #pragma unroll
    for (int i = 0; i < 5; i++) {
        int h = 32 >> i;
        int hi = lane & h;
        float2 o0 = shflx(v0, h);
        float2 o1 = shflx(v1, h);
        if (hi) {
            v0 = cmul(make_float2(o0.x - v0.x, o0.y - v0.y), w.t[i]);
            v1 = cmul(make_float2(o1.x - v1.x, o1.y - v1.y), w.t[i]);
        } else {
            v0 = make_float2(v0.x + o0.x, v0.y + o0.y);
            v1 = make_float2(v1.x + o1.x, v1.y + o1.y);
        }
    }
    int hi = lane & 1;
    float2 o0 = shflx(v0, 1);
    float2 o1 = shflx(v1, 1);
    v0 = hi ? make_float2(o0.x - v0.x, o0.y - v0.y) : make_float2(v0.x + o0.x, v0.y + o0.y);
    v1 = hi ? make_float2(o1.x - v1.x, o1.y - v1.y) : make_float2(v1.x + o1.x, v1.y + o1.y);
}

// slot index holding frequency k after fft128 (inverse of the output map)
__device__ __forceinline__ int slot_of(int k) {
    return (k & 1) ? 64 + rev6(k >> 1) : rev6(k >> 1);
}

// ---- Pass 1: packed x-FFT (L = mo + i*tg), Hermitian unpack, keep kx=0..64 ----
// grid: nb*128(z)*8(ytile) blocks of 256. Output layout: [vol][b][kx][z][y].
__global__ __launch_bounds__(256)
void fft_x_pack_kernel(const float* __restrict__ in0, const float* __restrict__ in1,
                       float2* __restrict__ wso, float2* __restrict__ wst,
                       int b0, float scale)
{
    __shared__ float2 tile[16][129];
    int tid = threadIdx.x, lane = tid & 63, wave = tid >> 6;
    int bi = blockIdx.x;
    int yt = bi & 7, z = (bi >> 3) & 127, b = bi >> 10;
    Tw w = make_tw(lane);

    size_t src_base = (size_t)(b0 + b) * VOL + (size_t)z * PLANE;
    #pragma unroll
    for (int c = 0; c < 4; c++) {
        int j = wave * 4 + c;
        const float* p0 = in0 + src_base + (size_t)(yt * 16 + j) * N;
        const float* p1 = in1 + src_base + (size_t)(yt * 16 + j) * N;
        float2 v0 = make_float2(p0[lane]      * scale, p1[lane]      * scale);
        float2 v1 = make_float2(p0[lane + 64] * scale, p1[lane + 64] * scale);
        fft128(v0, v1, w, lane);
        tile[j][lane]      = v0;      // slot = lane
        tile[j][lane + 64] = v1;      // slot = lane+64
    }
    __syncthreads();

    // unpack: O = (L(k)+conj(L(-k)))/2 ; T = (L(k)-conj(L(-k)))/(2i)
    size_t dst_off = (size_t)b * NKX * PLANE + (size_t)z * N + yt * 16;
    for (int idx = tid; idx < 2 * NKX * 16; idx += 256) {
        int j   = idx & 15;
        int c   = idx >> 4;              // 0..129
        int vol = (c >= NKX);
        int kx  = c - vol * NKX;
        int mk  = (128 - kx) & 127;
        float2 a  = tile[j][slot_of(kx)];
        float2 bm = tile[j][slot_of(mk)];
        float2 v = vol ? make_float2(0.5f * (a.y + bm.y), 0.5f * (bm.x - a.x))
                       : make_float2(0.5f * (a.x + bm.x), 0.5f * (a.y - bm.y));
        float2* dst = vol ? wst : wso;
        dst[dst_off + (size_t)kx * PLANE + j] = v;
    }
}

// ---- Pass 2: y-FFT on contiguous lines + transpose to [plane][ky-slot][z] ----
// grid: 2*nb*65*8 blocks of 256; block = (plane, ztile of 16)
__global__ __launch_bounds__(256)
void fft_y_transpose_kernel(const float2* __restrict__ src, float2* __restrict__ dst)
{
    __shared__ float2 tile[128][17];     // [ky-slot][z-within-tile], padded
    int tid = threadIdx.x, lane = tid & 63, wave = tid >> 6;
    int bi = blockIdx.x;
    int zt = bi & 7;
    size_t pv = (size_t)(bi >> 3);
    Tw w = make_tw(lane);

    size_t base = pv * PLANE;
    #pragma unroll
    for (int c = 0; c < 4; c++) {
        int j = wave * 4 + c;            // z index within tile
        const float2* p = src + base + (size_t)(zt * 16 + j) * N;
        float2 v0 = p[lane], v1 = p[lane + 64];
        fft128(v0, v1, w, lane);
        tile[lane][j]      = v0;
        tile[lane + 64][j] = v1;
    }
    __syncthreads();

    #pragma unroll
    for (int e = 0; e < 8; e++) {
        int idx = tid + 256 * e;
        int s = idx >> 4, j = idx & 15;
        dst[base + (size_t)s * N + zt * 16 + j] = tile[s][j];
    }
}

// ---- Pass 3: z-FFT from coalesced z-lines + fused weighted shell accumulation ----
// grid: nb*65*8 blocks of 256; block = (b, kx, slot-tile of 16)
__global__ __launch_bounds__(256)
void fft_z_acc_kernel(const float2* __restrict__ wsb, float* __restrict__ gacc,
                      int nb, int b0)
{
    __shared__ float accn[NSHELL], accp[NSHELL], accq[NSHELL];
    int tid = threadIdx.x, lane = tid & 63, wave = tid >> 6;
    int bi = blockIdx.x;
    int st8  = bi & 7;
    int rest = bi >> 3;
    int kx = rest % NKX;
    int b  = rest / NKX;
    Tw w = make_tw(lane);
    if (tid < NSHELL) { accn[tid] = 0.0f; accp[tid] = 0.0f; accq[tid] = 0.0f; }
    __syncthreads();

    size_t po = ((size_t)b * NKX + kx) * PLANE;
    size_t pt = ((size_t)(nb * NKX) + (size_t)b * NKX + kx) * PLANE;
    float wgt = (kx == 0 || kx == 64) ? 1.0f : 2.0f;   // Hermitian mirror weight
    int kx2 = kx * kx;
    int kz0 = 2 * rev6(lane), kz1 = kz0 + 1;
    int cz0 = (kz0 < 64) ? kz0 : kz0 - 128;
    int cz1 = (kz1 < 64) ? kz1 : kz1 - 128;
    int z20 = cz0 * cz0, z21 = cz1 * cz1;

    #pragma unroll
    for (int c = 0; c < 4; c++) {
        int s  = st8 * 16 + wave * 4 + c;              // ky-slot
        int ky = (s < 64) ? 2 * rev6(s) : 2 * rev6(s & 63) + 1;
        int cy = (ky < 64) ? ky : ky - 128;
        int base2 = kx2 + cy * cy;
        const float2* qo = wsb + po + (size_t)s * N;
        const float2* qt = wsb + pt + (size_t)s * N;
        float2 o0 = qo[lane], o1 = qo[lane + 64];
        float2 t0 = qt[lane], t1 = qt[lane + 64];
        fft128(o0, o1, w, lane);
        fft128(t0, t1, w, lane);
        int r20 = base2 + z20;
        if (r20 < 4225) {
            int sh = (int)sqrtf((float)r20);
            atomicAdd(&accn[sh], wgt * (o0.x * t0.x + o0.y * t0.y));
            atomicAdd(&accp[sh], wgt * (o0.x * o0.x + o0.y * o0.y));
            atomicAdd(&accq[sh], wgt * (t0.x * t0.x + t0.y * t0.y));
        }
        int r21 = base2 + z21;
        if (r21 < 4225) {
            int sh = (int)sqrtf((float)r21);
            atomicAdd(&accn[sh], wgt * (o1.x * t1.x + o1.y * t1.y));
            atomicAdd(&accp[sh], wgt * (o1.x * o1.x + o1.y * o1.y));
            atomicAdd(&accq[sh], wgt * (t1.x * t1.x + t1.y * t1.y));
        }
    }
    __syncthreads();

    if (tid < NSHELL) {
        float* g = gacc + (size_t)(b0 + b) * ACC_STRIDE;
        atomicAdd(&g[tid],              accn[tid]);
        atomicAdd(&g[NSHELL + tid],     accp[tid]);
        atomicAdd(&g[2 * NSHELL + tid], accq[tid]);
    }
}

// ---------------- Finalize: fsc -> loss scalar -----------------------------
__global__ void finalize_kernel(const float* __restrict__ gacc,
                                float* __restrict__ out)
{
    int lane = threadIdx.x;   // 64 threads, shell = lane+1 (1..64)
    int sh = lane + 1;
    float total = 0.0f;
    #pragma unroll
    for (int b = 0; b < 8; b++) {
        const float* g = gacc + b * ACC_STRIDE;
        float num = g[sh];
        float po  = g[NSHELL + sh];
        float pt  = g[2 * NSHELL + sh];
        float fsc = num / sqrtf(po * pt + 1e-6f);
        fsc = fminf(1.0f, fmaxf(-1.0f, fsc));
        total += fsc;
    }
    #pragma unroll
    for (int off = 32; off; off >>= 1) total += __shfl_down(total, off);
    if (lane == 0) out[0] = 1.0f - total / (64.0f * 8.0f);
}

extern "C" void kernel_launch(void* const* d_in, const int* in_sizes, int n_in,
                              void* d_out, int out_size, void* d_ws, size_t ws_size,
                              hipStream_t stream) {
    const float* in0 = (const float*)d_in[0];   // model_output (8,1,128,128,128)
    const float* in1 = (const float*)d_in[1];   // target
    float* gacc = (float*)d_ws;                 // 8*195 floats
    float2* wsA = (float2*)((char*)d_ws + 8192);

    hipMemsetAsync(d_ws, 0, 8 * ACC_STRIDE * sizeof(float), stream);

    size_t avail = (ws_size > 8192) ? ws_size - 8192 : 0;
    size_t per_batch = 4ull * NKX * PLANE * sizeof(float2);   // A + B, both vols ≈ 34 MB
    int NB = (int)(avail / per_batch);
    if (NB > 8) NB = 8;
    if (NB < 1) NB = 1;

    const float scale = 6.905339660024879e-4f;  // 1/sqrt(128^3)

    for (int b0 = 0; b0 < 8; b0 += NB) {
        int nb = (8 - b0 < NB) ? (8 - b0) : NB;
        size_t plane_cnt = (size_t)nb * NKX * PLANE;
        float2* wso = wsA;                       // A: [vol][b][kx][z][y]
        float2* wst = wsA + plane_cnt;
        float2* wsB = wsA + 2 * plane_cnt;       // B: [vol*b*kx][ky-slot][z]
        fft_x_pack_kernel<<<dim3(nb * 1024), dim3(256), 0, stream>>>(in0, in1, wso, wst, b0, scale);
        fft_y_transpose_kernel<<<dim3(nb * 1040), dim3(256), 0, stream>>>(wsA, wsB);
        fft_z_acc_kernel<<<dim3(nb * 520), dim3(256), 0, stream>>>(wsB, gacc, nb, b0);
    }
    finalize_kernel<<<dim3(1), dim3(64), 0, stream>>>(gacc, (float*)d_out);
}

// Round 4
// 341.249 us; speedup vs baseline: 2.0293x; 1.0996x over previous
//
#include <hip/hip_runtime.h>
#include <math.h>

#define N 128
#define VOL (N*N*N)            // 2097152
#define PLANE (N*N)            // 16384
#define NKX 65                 // kept x-frequencies 0..64 (Hermitian half)
#define NSHELL 65              // shells 0..64
#define ACC_STRIDE 195         // 3*65 per batch

__device__ __forceinline__ int rev6(int x) { return (int)(__brev((unsigned)x) >> 26); }

__device__ __forceinline__ float2 cmul(float2 a, float2 b) {
    return make_float2(a.x * b.x - a.y * b.y, a.x * b.y + a.y * b.x);
}
__device__ __forceinline__ float2 shflx(float2 v, int m) {
    return make_float2(__shfl_xor(v.x, m), __shfl_xor(v.y, m));
}

// bf16x2 pack (RNE) / unpack: complex value in one uint (re low, im high)
__device__ __forceinline__ unsigned int pack_bf2(float2 v) {
    unsigned int r = __float_as_uint(v.x);
    unsigned int i = __float_as_uint(v.y);
    r = (r + 0x7FFFu + ((r >> 16) & 1u)) >> 16;
    i = (i + 0x7FFFu + ((i >> 16) & 1u)) & 0xFFFF0000u;
    return i | r;
}
__device__ __forceinline__ float2 unpack_bf2(unsigned int u) {
    return make_float2(__uint_as_float(u << 16), __uint_as_float(u & 0xFFFF0000u));
}

// Per-lane twiddles for the register-resident 128-pt DIF FFT
struct Tw { float2 w128; float2 t[5]; };

__device__ __forceinline__ Tw make_tw(int lane) {
    Tw w; float s, c;
    sincosf(-6.283185307179586f * (float)lane / 128.0f, &s, &c);
    w.w128 = make_float2(c, s);
    #pragma unroll
    for (int i = 0; i < 5; i++) {
        int h = 32 >> i;
        int j = lane & (h - 1);
        sincosf(-6.283185307179586f * (float)j / (float)(2 * h), &s, &c);
        w.t[i] = make_float2(c, s);
    }
    return w;
}

// 128-pt DIF FFT, wave-resident: lane holds x[lane] (v0) and x[lane+64] (v1).
// Output: v0 = X[2*rev6(lane)], v1 = X[2*rev6(lane)+1].
__device__ __forceinline__ void fft128(float2& v0, float2& v1, const Tw& w, int lane) {
    float2 d = make_float2(v0.x - v1.x, v0.y - v1.y);
    v0 = make_float2(v0.x + v1.x, v0.y + v1.y);
    v1 = cmul(d, w.w128);
    #pragma unroll
    for (int i = 0; i < 5; i++) {
        int h = 32 >> i;
        int hi = lane & h;
        float2 o0 = shflx(v0, h);
        float2 o1 = shflx(v1, h);
        if (hi) {
            v0 = cmul(make_float2(o0.x - v0.x, o0.y - v0.y), w.t[i]);
            v1 = cmul(make_float2(o1.x - v1.x, o1.y - v1.y), w.t[i]);
        } else {
            v0 = make_float2(v0.x + o0.x, v0.y + o0.y);
            v1 = make_float2(v1.x + o1.x, v1.y + o1.y);
        }
    }
    int hi = lane & 1;
    float2 o0 = shflx(v0, 1);
    float2 o1 = shflx(v1, 1);
    v0 = hi ? make_float2(o0.x - v0.x, o0.y - v0.y) : make_float2(v0.x + o0.x, v0.y + o0.y);
    v1 = hi ? make_float2(o1.x - v1.x, o1.y - v1.y) : make_float2(v1.x + o1.x, v1.y + o1.y);
}

// slot index holding frequency k after fft128
__device__ __forceinline__ int slot_of(int k) {
    return (k & 1) ? 64 + rev6(k >> 1) : rev6(k >> 1);
}

// ---- Pass 1: packed x-FFT (L = mo + i*tg), Hermitian unpack, keep kx=0..64 ----
// grid: nb*128(z)*8(ytile) blocks of 256. Output (bf16x2): [vol][b][kx][z][y].
__global__ __launch_bounds__(256)
void fft_x_pack_kernel(const float* __restrict__ in0, const float* __restrict__ in1,
                       unsigned int* __restrict__ wso, unsigned int* __restrict__ wst,
                       int b0, float scale)
{
    __shared__ float2 tile[16][129];
    int tid = threadIdx.x, lane = tid & 63, wave = tid >> 6;
    int bi = blockIdx.x;
    int yt = bi & 7, z = (bi >> 3) & 127, b = bi >> 10;
    Tw w = make_tw(lane);

    size_t src_base = (size_t)(b0 + b) * VOL + (size_t)z * PLANE;
    #pragma unroll
    for (int c = 0; c < 4; c++) {
        int j = wave * 4 + c;
        const float* p0 = in0 + src_base + (size_t)(yt * 16 + j) * N;
        const float* p1 = in1 + src_base + (size_t)(yt * 16 + j) * N;
        float2 v0 = make_float2(p0[lane]      * scale, p1[lane]      * scale);
        float2 v1 = make_float2(p0[lane + 64] * scale, p1[lane + 64] * scale);
        fft128(v0, v1, w, lane);
        tile[j][lane]      = v0;
        tile[j][lane + 64] = v1;
    }
    __syncthreads();

    // unpack: O = (L(k)+conj(L(-k)))/2 ; T = (L(k)-conj(L(-k)))/(2i)
    size_t dst_off = (size_t)b * NKX * PLANE + (size_t)z * N + yt * 16;
    for (int idx = tid; idx < 2 * NKX * 16; idx += 256) {
        int j   = idx & 15;
        int c   = idx >> 4;              // 0..129
        int vol = (c >= NKX);
        int kx  = c - vol * NKX;
        int mk  = (128 - kx) & 127;
        float2 a  = tile[j][slot_of(kx)];
        float2 bm = tile[j][slot_of(mk)];
        float2 v = vol ? make_float2(0.5f * (a.y + bm.y), 0.5f * (bm.x - a.x))
                       : make_float2(0.5f * (a.x + bm.x), 0.5f * (a.y - bm.y));
        unsigned int* dst = vol ? wst : wso;
        dst[dst_off + (size_t)kx * PLANE + j] = pack_bf2(v);
    }
}

// ---- Fused pass 2: y-FFT + z-FFT + shell accumulation per (b, kx) plane ----
// grid: nb*65 blocks of 1024 (16 waves). LDS: both vols' planes as bf16x2.
// Layout: tile[vol][ky][(z + (ky>>2)) & 127]  (swizzle -> 2-way banks everywhere)
__global__ __launch_bounds__(1024)
void fft_yz_acc_kernel(const unsigned int* __restrict__ wsv, float* __restrict__ gacc,
                       int nb, int b0)
{
    __shared__ unsigned int tile[2][128][128];   // 131072 B
    __shared__ float accn[NSHELL], accp[NSHELL], accq[NSHELL];
    int tid = threadIdx.x, lane = tid & 63, wave = tid >> 6;
    int bi = blockIdx.x;
    int kx = bi % NKX, b = bi / NKX;
    Tw w = make_tw(lane);
    if (tid < NSHELL) { accn[tid] = 0.0f; accp[tid] = 0.0f; accq[tid] = 0.0f; }

    // Phase A: 256 y-FFT lines (vol, z); wave handles 16
    int nv = nb * NKX;
    #pragma unroll 2
    for (int c = 0; c < 16; c++) {
        int idx = wave * 16 + c;
        int vol = idx >> 7, z = idx & 127;
        const unsigned int* p = wsv + ((size_t)vol * nv + (size_t)b * NKX + kx) * PLANE + (size_t)z * N;
        float2 v0 = unpack_bf2(p[lane]);
        float2 v1 = unpack_bf2(p[lane + 64]);
        fft128(v0, v1, w, lane);
        int ky0 = 2 * rev6(lane);                // v1 holds ky0+1
        int col = (z + (ky0 >> 2)) & 127;        // same col for ky0 and ky0+1
        tile[vol][ky0][col]     = pack_bf2(v0);
        tile[vol][ky0 + 1][col] = pack_bf2(v1);
    }
    __syncthreads();

    // Phase B: z-FFT per live ky line + accumulate
    int kx2 = kx * kx;
    int kz0 = 2 * rev6(lane), kz1 = kz0 + 1;
    int cz0 = (kz0 < 64) ? kz0 : kz0 - 128;
    int cz1 = (kz1 < 64) ? kz1 : kz1 - 128;
    int z20 = cz0 * cz0, z21 = cz1 * cz1;

    for (int c = 0; c < 8; c++) {
        int ky = wave + 16 * c;
        int cy = (ky < 64) ? ky : ky - 128;
        int base2 = kx2 + cy * cy;
        if (base2 > 4224) continue;              // whole z-line outside sphere
        int off = ky >> 2;
        int c0 = (lane + off) & 127;
        int c1 = (lane + 64 + off) & 127;
        float2 o0 = unpack_bf2(tile[0][ky][c0]);
        float2 o1 = unpack_bf2(tile[0][ky][c1]);
        float2 t0 = unpack_bf2(tile[1][ky][c0]);
        float2 t1 = unpack_bf2(tile[1][ky][c1]);
        fft128(o0, o1, w, lane);
        fft128(t0, t1, w, lane);
        int r20 = base2 + z20;
        if (r20 <= 4224) {
            int sh = (int)sqrtf((float)r20);
            if ((sh + 1) * (sh + 1) <= r20) sh++;
            else if (sh * sh > r20) sh--;
            atomicAdd(&accn[sh], o0.x * t0.x + o0.y * t0.y);
            atomicAdd(&accp[sh], o0.x * o0.x + o0.y * o0.y);
            atomicAdd(&accq[sh], t0.x * t0.x + t0.y * t0.y);
        }
        int r21 = base2 + z21;
        if (r21 <= 4224) {
            int sh = (int)sqrtf((float)r21);
            if ((sh + 1) * (sh + 1) <= r21) sh++;
            else if (sh * sh > r21) sh--;
            atomicAdd(&accn[sh], o1.x * t1.x + o1.y * t1.y);
            atomicAdd(&accp[sh], o1.x * o1.x + o1.y * o1.y);
            atomicAdd(&accq[sh], t1.x * t1.x + t1.y * t1.y);
        }
    }
    __syncthreads();

    if (tid < NSHELL) {
        float wgt = (kx == 0 || kx == 64) ? 1.0f : 2.0f;   // Hermitian mirror weight
        float* g = gacc + (size_t)(b0 + b) * ACC_STRIDE;
        atomicAdd(&g[tid],              wgt * accn[tid]);
        atomicAdd(&g[NSHELL + tid],     wgt * accp[tid]);
        atomicAdd(&g[2 * NSHELL + tid], wgt * accq[tid]);
    }
}

// ---------------- Finalize: fsc -> loss scalar -----------------------------
__global__ void finalize_kernel(const float* __restrict__ gacc,
                                float* __restrict__ out)
{
    int lane = threadIdx.x;   // 64 threads, shell = lane+1 (1..64)
    int sh = lane + 1;
    float total = 0.0f;
    #pragma unroll
    for (int b = 0; b < 8; b++) {
        const float* g = gacc + b * ACC_STRIDE;
        float num = g[sh];
        float po  = g[NSHELL + sh];
        float pt  = g[2 * NSHELL + sh];
        float fsc = num / sqrtf(po * pt + 1e-6f);
        fsc = fminf(1.0f, fmaxf(-1.0f, fsc));
        total += fsc;
    }
    #pragma unroll
    for (int off = 32; off; off >>= 1) total += __shfl_down(total, off);
    if (lane == 0) out[0] = 1.0f - total / (64.0f * 8.0f);
}

extern "C" void kernel_launch(void* const* d_in, const int* in_sizes, int n_in,
                              void* d_out, int out_size, void* d_ws, size_t ws_size,
                              hipStream_t stream) {
    const float* in0 = (const float*)d_in[0];   // model_output (8,1,128,128,128)
    const float* in1 = (const float*)d_in[1];   // target
    float* gacc = (float*)d_ws;                 // 8*195 floats
    unsigned int* wsA = (unsigned int*)((char*)d_ws + 8192);

    hipMemsetAsync(d_ws, 0, 8 * ACC_STRIDE * sizeof(float), stream);

    size_t avail = (ws_size > 8192) ? ws_size - 8192 : 0;
    size_t per_batch = 2ull * NKX * PLANE * sizeof(unsigned int);   // ~8.5 MB
    int NB = (int)(avail / per_batch);
    if (NB > 8) NB = 8;
    if (NB < 1) NB = 1;

    const float scale = 6.905339660024879e-4f;  // 1/sqrt(128^3)

    for (int b0 = 0; b0 < 8; b0 += NB) {
        int nb = (8 - b0 < NB) ? (8 - b0) : NB;
        size_t plane_cnt = (size_t)nb * NKX * PLANE;
        unsigned int* wso = wsA;                 // [vol][b][kx][z][y] bf16x2
        unsigned int* wst = wsA + plane_cnt;
        fft_x_pack_kernel<<<dim3(nb * 1024), dim3(256), 0, stream>>>(in0, in1, wso, wst, b0, scale);
        fft_yz_acc_kernel<<<dim3(nb * NKX), dim3(1024), 0, stream>>>(wsA, gacc, nb, b0);
    }
    finalize_kernel<<<dim3(1), dim3(64), 0, stream>>>(gacc, (float*)d_out);
}

// Round 5
// 329.412 us; speedup vs baseline: 2.1022x; 1.0359x over previous
//
#include <hip/hip_runtime.h>
#include <math.h>

#define N 128
#define VOL (N*N*N)            // 2097152
#define PLANE (N*N)            // 16384
#define NKX 65                 // kept x-frequencies 0..64 (Hermitian half)
#define NSHELL 65              // shells 0..64
#define ACC_STRIDE 195         // 3*65 per batch

typedef float vf2 __attribute__((ext_vector_type(2)));

__device__ __forceinline__ int rev6(int x) { return (int)(__brev((unsigned)x) >> 26); }

__device__ __forceinline__ float2 shflx(float2 v, int m) {
    return make_float2(__shfl_xor(v.x, m), __shfl_xor(v.y, m));
}

// bf16x2 pack (RNE) / unpack: complex value in one uint (re low, im high)
__device__ __forceinline__ unsigned int pack_bf2(float2 v) {
    unsigned int r = __float_as_uint(v.x);
    unsigned int i = __float_as_uint(v.y);
    r = (r + 0x7FFFu + ((r >> 16) & 1u)) >> 16;
    i = (i + 0x7FFFu + ((i >> 16) & 1u)) & 0xFFFF0000u;
    return i | r;
}
__device__ __forceinline__ float2 unpack_bf2(unsigned int u) {
    return make_float2(__uint_as_float(u << 16), __uint_as_float(u & 0xFFFF0000u));
}

// fp8 e4m3 packed complex (re byte0, im byte1) for the in-LDS plane
__device__ __forceinline__ unsigned short pack_f8(float2 v) {
    int p = __builtin_amdgcn_cvt_pk_fp8_f32(v.x, v.y, 0, false);
    return (unsigned short)(p & 0xFFFF);
}
__device__ __forceinline__ float2 unpack_f8(unsigned short u) {
    auto r = __builtin_amdgcn_cvt_pk_f32_fp8((int)u, false);
    return make_float2(r[0], r[1]);
}

// 64-entry twiddle table W[m] = e^{-2*pi*i*m/128}, built once per block
__device__ __forceinline__ void build_W(float2* Wsh, int tid) {
    if (tid < 64) {
        float s, c;
        sincosf(-6.283185307179586f * (float)tid / 128.0f, &s, &c);
        Wsh[tid] = make_float2(c, s);
    }
}

// Per-lane effective twiddles: w128 for the register stage; we[i] is the
// stage twiddle for high lanes and (1,0) for low lanes (branchless butterfly).
struct TwE { float2 w128; float2 we[5]; };

__device__ __forceinline__ TwE make_twe(const float2* Wsh, int lane) {
    TwE w;
    w.w128 = Wsh[lane];
    #pragma unroll
    for (int i = 0; i < 5; i++) {
        int h = 32 >> i;
        float2 t = Wsh[(lane & (h - 1)) << (i + 1)];
        w.we[i] = (lane & h) ? t : make_float2(1.0f, 0.0f);
    }
    return w;
}

__device__ __forceinline__ void bstage(float2& v, float2 o, float s, float2 we) {
    float tx = fmaf(s, v.x, o.x);
    float ty = fmaf(s, v.y, o.y);
    v = make_float2(tx * we.x - ty * we.y, tx * we.y + ty * we.x);
}

// 128-pt DIF FFT, wave-resident, branchless: lane holds x[lane], x[lane+64].
// Output: v0 = X[2*rev6(lane)], v1 = X[2*rev6(lane)+1].
__device__ __forceinline__ void fft128(float2& v0, float2& v1, const TwE& w, int lane) {
    float2 d = make_float2(v0.x - v1.x, v0.y - v1.y);
    v0 = make_float2(v0.x + v1.x, v0.y + v1.y);
    v1 = make_float2(d.x * w.w128.x - d.y * w.w128.y, d.x * w.w128.y + d.y * w.w128.x);
    #pragma unroll
    for (int i = 0; i < 5; i++) {
        int h = 32 >> i;
        float s = (lane & h) ? -1.0f : 1.0f;
        float2 o0 = shflx(v0, h);
        float2 o1 = shflx(v1, h);
        bstage(v0, o0, s, w.we[i]);
        bstage(v1, o1, s, w.we[i]);
    }
    float s = (lane & 1) ? -1.0f : 1.0f;
    float2 o0 = shflx(v0, 1);
    float2 o1 = shflx(v1, 1);
    v0 = make_float2(fmaf(s, v0.x, o0.x), fmaf(s, v0.y, o0.y));
    v1 = make_float2(fmaf(s, v1.x, o1.x), fmaf(s, v1.y, o1.y));
}

// slot index holding frequency k after fft128
__device__ __forceinline__ int slot_of(int k) {
    return (k & 1) ? 64 + rev6(k >> 1) : rev6(k >> 1);
}

// ---- Pass 1: packed x-FFT (L = mo + i*tg), Hermitian unpack, keep kx=0..64 ----
// grid: nb*128(z)*8(ytile) blocks of 256. Output (bf16x2): [vol][b][kx][z][y].
__global__ __launch_bounds__(256, 8)
void fft_x_pack_kernel(const float* __restrict__ in0, const float* __restrict__ in1,
                       unsigned int* __restrict__ wso, unsigned int* __restrict__ wst,
                       int b0, float scale)
{
    __shared__ float2 tile[16][129];
    __shared__ float2 Wsh[64];
    int tid = threadIdx.x, lane = tid & 63, wave = tid >> 6;
    int bi = blockIdx.x;
    int yt = bi & 7, z = (bi >> 3) & 127, b = bi >> 10;
    build_W(Wsh, tid);
    __syncthreads();
    TwE w = make_twe(Wsh, lane);

    size_t src_base = (size_t)(b0 + b) * VOL + (size_t)z * PLANE;
    #pragma unroll
    for (int c = 0; c < 4; c++) {
        int j = wave * 4 + c;
        const float* p0 = in0 + src_base + (size_t)(yt * 16 + j) * N;
        const float* p1 = in1 + src_base + (size_t)(yt * 16 + j) * N;
        float2 v0 = make_float2(p0[lane]      * scale, p1[lane]      * scale);
        float2 v1 = make_float2(p0[lane + 64] * scale, p1[lane + 64] * scale);
        fft128(v0, v1, w, lane);
        tile[j][lane]      = v0;
        tile[j][lane + 64] = v1;
    }
    __syncthreads();

    // unpack: O = (L(k)+conj(L(-k)))/2 ; T = (L(k)-conj(L(-k)))/(2i)
    size_t dst_off = (size_t)b * NKX * PLANE + (size_t)z * N + yt * 16;
    for (int idx = tid; idx < 2 * NKX * 16; idx += 256) {
        int j   = idx & 15;
        int c   = idx >> 4;              // 0..129
        int vol = (c >= NKX);
        int kx  = c - vol * NKX;
        int mk  = (128 - kx) & 127;
        float2 a  = tile[j][slot_of(kx)];
        float2 bm = tile[j][slot_of(mk)];
        float2 v = vol ? make_float2(0.5f * (a.y + bm.y), 0.5f * (bm.x - a.x))
                       : make_float2(0.5f * (a.x + bm.x), 0.5f * (a.y - bm.y));
        unsigned int* dst = vol ? wst : wso;
        dst[dst_off + (size_t)kx * PLANE + j] = pack_bf2(v);
    }
}

// ---- Fused pass 2: y-FFT + z-FFT + shell accumulation per (b, kx) plane ----
// grid: nb*65 blocks of 1024 (16 waves). LDS plane as fp8x2 (values ×16 from
// pass1's scale; all three shell sums scale by exactly 256, undone at flush).
// Swizzle col = (z + ky) & 127: Phase-A writes 2-way (free), Phase-B reads
// consecutive (free).
__global__ __launch_bounds__(1024, 8)
void fft_yz_acc_kernel(const unsigned int* __restrict__ wsv, float* __restrict__ gacc,
                       int nb, int b0)
{
    __shared__ unsigned short tile[2][128][128];   // 65536 B
    __shared__ float2 Wsh[64];
    __shared__ float accn[NSHELL], accp[NSHELL], accq[NSHELL];
    int tid = threadIdx.x, lane = tid & 63, wave = tid >> 6;
    int bi = blockIdx.x;
    int kx = bi % NKX, b = bi / NKX;
    build_W(Wsh, tid);
    if (tid >= 64 && tid < 64 + NSHELL) {
        int s0 = tid - 64;
        accn[s0] = 0.0f; accp[s0] = 0.0f; accq[s0] = 0.0f;
    }
    __syncthreads();
    TwE w = make_twe(Wsh, lane);

    // Phase A: 256 y-FFT lines (vol, z); wave handles 16
    int nv = nb * NKX;
    #pragma unroll 2
    for (int c = 0; c < 16; c++) {
        int idx = wave * 16 + c;
        int vol = idx >> 7, z = idx & 127;
        const unsigned int* p = wsv + ((size_t)vol * nv + (size_t)b * NKX + kx) * PLANE + (size_t)z * N;
        float2 v0 = unpack_bf2(p[lane]);
        float2 v1 = unpack_bf2(p[lane + 64]);
        fft128(v0, v1, w, lane);
        int ky0 = 2 * rev6(lane);                // v1 holds ky0+1
        tile[vol][ky0][(z + ky0) & 127]         = pack_f8(v0);
        tile[vol][ky0 + 1][(z + ky0 + 1) & 127] = pack_f8(v1);
    }
    __syncthreads();

    // Phase B: z-FFT per live ky line + accumulate
    int kx2 = kx * kx;
    int kz0 = 2 * rev6(lane), kz1 = kz0 + 1;
    int cz0 = (kz0 < 64) ? kz0 : kz0 - 128;
    int cz1 = (kz1 < 64) ? kz1 : kz1 - 128;
    int z20 = cz0 * cz0, z21 = cz1 * cz1;

    for (int c = 0; c < 8; c++) {
        int ky = wave + 16 * c;
        int cy = (ky < 64) ? ky : ky - 128;
        int base2 = kx2 + cy * cy;
        if (base2 > 4224) continue;              // whole z-line outside sphere
        int c0 = (lane + ky) & 127;
        int c1 = (lane + 64 + ky) & 127;
        float2 o0 = unpack_f8(tile[0][ky][c0]);
        float2 o1 = unpack_f8(tile[0][ky][c1]);
        float2 t0 = unpack_f8(tile[1][ky][c0]);
        float2 t1 = unpack_f8(tile[1][ky][c1]);
        fft128(o0, o1, w, lane);
        fft128(t0, t1, w, lane);
        int r20 = base2 + z20;
        if (r20 <= 4224) {
            int sh = (int)sqrtf((float)r20);
            if ((sh + 1) * (sh + 1) <= r20) sh++;
            else if (sh * sh > r20) sh--;
            atomicAdd(&accn[sh], o0.x * t0.x + o0.y * t0.y);
            atomicAdd(&accp[sh], o0.x * o0.x + o0.y * o0.y);
            atomicAdd(&accq[sh], t0.x * t0.x + t0.y * t0.y);
        }
        int r21 = base2 + z21;
        if (r21 <= 4224) {
            int sh = (int)sqrtf((float)r21);
            if ((sh + 1) * (sh + 1) <= r21) sh++;
            else if (sh * sh > r21) sh--;
            atomicAdd(&accn[sh], o1.x * t1.x + o1.y * t1.y);
            atomicAdd(&accp[sh], o1.x * o1.x + o1.y * o1.y);
            atomicAdd(&accq[sh], t1.x * t1.x + t1.y * t1.y);
        }
    }
    __syncthreads();

    if (tid < NSHELL) {
        // Hermitian mirror weight * 1/256 (undo the ×16 amplitude pre-scale)
        float wgt = ((kx == 0 || kx == 64) ? 1.0f : 2.0f) * (1.0f / 256.0f);
        float* g = gacc + (size_t)(b0 + b) * ACC_STRIDE;
        atomicAdd(&g[tid],              wgt * accn[tid]);
        atomicAdd(&g[NSHELL + tid],     wgt * accp[tid]);
        atomicAdd(&g[2 * NSHELL + tid], wgt * accq[tid]);
    }
}

// ---------------- Finalize: fsc -> loss scalar -----------------------------
__global__ void finalize_kernel(const float* __restrict__ gacc,
                                float* __restrict__ out)
{
    int lane = threadIdx.x;   // 64 threads, shell = lane+1 (1..64)
    int sh = lane + 1;
    float total = 0.0f;
    #pragma unroll
    for (int b = 0; b < 8; b++) {
        const float* g = gacc + b * ACC_STRIDE;
        float num = g[sh];
        float po  = g[NSHELL + sh];
        float pt  = g[2 * NSHELL + sh];
        float fsc = num / sqrtf(po * pt + 1e-6f);
        fsc = fminf(1.0f, fmaxf(-1.0f, fsc));
        total += fsc;
    }
    #pragma unroll
    for (int off = 32; off; off >>= 1) total += __shfl_down(total, off);
    if (lane == 0) out[0] = 1.0f - total / (64.0f * 8.0f);
}

extern "C" void kernel_launch(void* const* d_in, const int* in_sizes, int n_in,
                              void* d_out, int out_size, void* d_ws, size_t ws_size,
                              hipStream_t stream) {
    const float* in0 = (const float*)d_in[0];   // model_output (8,1,128,128,128)
    const float* in1 = (const float*)d_in[1];   // target
    float* gacc = (float*)d_ws;                 // 8*195 floats
    unsigned int* wsA = (unsigned int*)((char*)d_ws + 8192);

    hipMemsetAsync(d_ws, 0, 8 * ACC_STRIDE * sizeof(float), stream);

    size_t avail = (ws_size > 8192) ? ws_size - 8192 : 0;
    size_t per_batch = 2ull * NKX * PLANE * sizeof(unsigned int);   // ~8.5 MB
    int NB = (int)(avail / per_batch);
    if (NB > 8) NB = 8;
    if (NB < 1) NB = 1;

    // 16 / sqrt(128^3): ortho norm plus ×16 amplitude pre-scale so the fp8
    // LDS plane sits in e4m3's sweet spot; shell sums are ×256, undone at flush.
    const float scale = 1.1048543456039804e-2f;

    for (int b0 = 0; b0 < 8; b0 += NB) {
        int nb = (8 - b0 < NB) ? (8 - b0) : NB;
        size_t plane_cnt = (size_t)nb * NKX * PLANE;
        unsigned int* wso = wsA;                 // [vol][b][kx][z][y] bf16x2
        unsigned int* wst = wsA + plane_cnt;
        fft_x_pack_kernel<<<dim3(nb * 1024), dim3(256), 0, stream>>>(in0, in1, wso, wst, b0, scale);
        fft_yz_acc_kernel<<<dim3(nb * NKX), dim3(1024), 0, stream>>>(wsA, gacc, nb, b0);
    }
    finalize_kernel<<<dim3(1), dim3(64), 0, stream>>>(gacc, (float*)d_out);
}

// Round 6
// 327.260 us; speedup vs baseline: 2.1160x; 1.0066x over previous
//
#include <hip/hip_runtime.h>
#include <math.h>

#define N 128
#define VOL (N*N*N)            // 2097152
#define PLANE (N*N)            // 16384
#define NKX 65                 // kept x-frequencies 0..64 (Hermitian half)
#define NSHELL 65              // shells 0..64
#define ACC_STRIDE 195         // 3*65 per batch

__device__ __forceinline__ int rev6(int x) { return (int)(__brev((unsigned)x) >> 26); }

__device__ __forceinline__ float2 shflx(float2 v, int m) {
    return make_float2(__shfl_xor(v.x, m), __shfl_xor(v.y, m));
}
__device__ __forceinline__ float2 cmul(float2 a, float2 b) {
    return make_float2(a.x * b.x - a.y * b.y, a.x * b.y + a.y * b.x);
}

// bf16x2 pack (RNE) / unpack: complex value in one uint (re low, im high)
__device__ __forceinline__ unsigned int pack_bf2(float2 v) {
    unsigned int r = __float_as_uint(v.x);
    unsigned int i = __float_as_uint(v.y);
    r = (r + 0x7FFFu + ((r >> 16) & 1u)) >> 16;
    i = (i + 0x7FFFu + ((i >> 16) & 1u)) & 0xFFFF0000u;
    return i | r;
}
__device__ __forceinline__ float2 unpack_bf2(unsigned int u) {
    return make_float2(__uint_as_float(u << 16), __uint_as_float(u & 0xFFFF0000u));
}

// fp8 e4m3 packed complex (re byte0, im byte1) for the in-LDS plane
__device__ __forceinline__ unsigned short pack_f8(float2 v) {
    int p = __builtin_amdgcn_cvt_pk_fp8_f32(v.x, v.y, 0, false);
    return (unsigned short)(p & 0xFFFF);
}
__device__ __forceinline__ float2 unpack_f8(unsigned short u) {
    auto r = __builtin_amdgcn_cvt_pk_f32_fp8((int)u, false);
    return make_float2(r[0], r[1]);
}

// 64-entry twiddle table W[m] = e^{-2*pi*i*m/128}, built once per block
__device__ __forceinline__ void build_W(float2* Wsh, int tid) {
    if (tid < 64) {
        float s, c;
        sincosf(-6.283185307179586f * (float)tid / 128.0f, &s, &c);
        Wsh[tid] = make_float2(c, s);
    }
}

// Per-lane effective twiddles: w128 for the register stage; we[i] is the
// stage twiddle for high lanes and (1,0) for low lanes (branchless butterfly).
struct TwE { float2 w128; float2 we[5]; };

__device__ __forceinline__ TwE make_twe(const float2* Wsh, int lane) {
    TwE w;
    w.w128 = Wsh[lane];
    #pragma unroll
    for (int i = 0; i < 5; i++) {
        int h = 32 >> i;
        float2 t = Wsh[(lane & (h - 1)) << (i + 1)];
        w.we[i] = (lane & h) ? t : make_float2(1.0f, 0.0f);
    }
    return w;
}

__device__ __forceinline__ void bstage(float2& v, float2 o, float s, float2 we) {
    float tx = fmaf(s, v.x, o.x);
    float ty = fmaf(s, v.y, o.y);
    v = make_float2(tx * we.x - ty * we.y, tx * we.y + ty * we.x);
}

// Two independent 128-pt DIF FFTs, interleaved stage-by-stage so the 8 b32
// shuffles per stage issue back-to-back (covers ds_bpermute latency).
// Pair A: lane holds a0=x[lane], a1=x[lane+64]; same for pair B.
// Output: a0 = X[2*rev6(lane)], a1 = X[2*rev6(lane)+1].
__device__ __forceinline__ void fft128x2(float2& a0, float2& a1,
                                         float2& b0, float2& b1,
                                         const TwE& w, int lane) {
    float2 d;
    d  = make_float2(a0.x - a1.x, a0.y - a1.y);
    a0 = make_float2(a0.x + a1.x, a0.y + a1.y);
    a1 = cmul(d, w.w128);
    d  = make_float2(b0.x - b1.x, b0.y - b1.y);
    b0 = make_float2(b0.x + b1.x, b0.y + b1.y);
    b1 = cmul(d, w.w128);
    #pragma unroll
    for (int i = 0; i < 5; i++) {
        int h = 32 >> i;
        float s = (lane & h) ? -1.0f : 1.0f;
        float2 oa0 = shflx(a0, h);
        float2 oa1 = shflx(a1, h);
        float2 ob0 = shflx(b0, h);
        float2 ob1 = shflx(b1, h);
        bstage(a0, oa0, s, w.we[i]);
        bstage(a1, oa1, s, w.we[i]);
        bstage(b0, ob0, s, w.we[i]);
        bstage(b1, ob1, s, w.we[i]);
    }
    float s = (lane & 1) ? -1.0f : 1.0f;
    float2 oa0 = shflx(a0, 1);
    float2 oa1 = shflx(a1, 1);
    float2 ob0 = shflx(b0, 1);
    float2 ob1 = shflx(b1, 1);
    a0 = make_float2(fmaf(s, a0.x, oa0.x), fmaf(s, a0.y, oa0.y));
    a1 = make_float2(fmaf(s, a1.x, oa1.x), fmaf(s, a1.y, oa1.y));
    b0 = make_float2(fmaf(s, b0.x, ob0.x), fmaf(s, b0.y, ob0.y));
    b1 = make_float2(fmaf(s, b1.x, ob1.x), fmaf(s, b1.y, ob1.y));
}

// slot index holding frequency k after fft128
__device__ __forceinline__ int slot_of(int k) {
    return (k & 1) ? 64 + rev6(k >> 1) : rev6(k >> 1);
}

// ---- Pass 1: packed x-FFT (L = mo + i*tg), Hermitian unpack, keep kx=0..64 ----
// grid: nb*128(z)*8(ytile) blocks of 256. Output (bf16x2): [vol][b][kx][z][y].
__global__ __launch_bounds__(256, 8)
void fft_x_pack_kernel(const float* __restrict__ in0, const float* __restrict__ in1,
                       unsigned int* __restrict__ wso, unsigned int* __restrict__ wst,
                       int b0, float scale)
{
    __shared__ float2 tile[16][129];
    __shared__ float2 Wsh[64];
    int tid = threadIdx.x, lane = tid & 63, wave = tid >> 6;
    int bi = blockIdx.x;
    int yt = bi & 7, z = (bi >> 3) & 127, b = bi >> 10;
    build_W(Wsh, tid);
    __syncthreads();
    TwE w = make_twe(Wsh, lane);

    size_t src_base = (size_t)(b0 + b) * VOL + (size_t)z * PLANE;
    #pragma unroll
    for (int c = 0; c < 4; c += 2) {
        int j0 = wave * 4 + c, j1 = j0 + 1;
        const float* pa0 = in0 + src_base + (size_t)(yt * 16 + j0) * N;
        const float* pa1 = in1 + src_base + (size_t)(yt * 16 + j0) * N;
        const float* pb0 = in0 + src_base + (size_t)(yt * 16 + j1) * N;
        const float* pb1 = in1 + src_base + (size_t)(yt * 16 + j1) * N;
        float2 a0 = make_float2(pa0[lane]      * scale, pa1[lane]      * scale);
        float2 a1 = make_float2(pa0[lane + 64] * scale, pa1[lane + 64] * scale);
        float2 c0 = make_float2(pb0[lane]      * scale, pb1[lane]      * scale);
        float2 c1 = make_float2(pb0[lane + 64] * scale, pb1[lane + 64] * scale);
        fft128x2(a0, a1, c0, c1, w, lane);
        tile[j0][lane]      = a0;
        tile[j0][lane + 64] = a1;
        tile[j1][lane]      = c0;
        tile[j1][lane + 64] = c1;
    }
    __syncthreads();

    // unpack: O = (L(k)+conj(L(-k)))/2 ; T = (L(k)-conj(L(-k)))/(2i)
    size_t dst_off = (size_t)b * NKX * PLANE + (size_t)z * N + yt * 16;
    for (int idx = tid; idx < 2 * NKX * 16; idx += 256) {
        int j   = idx & 15;
        int c   = idx >> 4;              // 0..129
        int vol = (c >= NKX);
        int kx  = c - vol * NKX;
        int mk  = (128 - kx) & 127;
        float2 a  = tile[j][slot_of(kx)];
        float2 bm = tile[j][slot_of(mk)];
        float2 v = vol ? make_float2(0.5f * (a.y + bm.y), 0.5f * (bm.x - a.x))
                       : make_float2(0.5f * (a.x + bm.x), 0.5f * (a.y - bm.y));
        unsigned int* dst = vol ? wst : wso;
        dst[dst_off + (size_t)kx * PLANE + j] = pack_bf2(v);
    }
}

// ---- Fused pass 2: y-FFT + z-FFT + shell accumulation per (b, kx) plane ----
// grid: nb*65 blocks of 1024 (16 waves). LDS plane as fp8x2 (values ×16 from
// pass1's scale; all three shell sums scale by exactly 256, undone at flush).
// Swizzle col = (z + ky) & 127: Phase-A writes 2-way (free), Phase-B reads
// consecutive (free).
__global__ __launch_bounds__(1024, 8)
void fft_yz_acc_kernel(const unsigned int* __restrict__ wsv, float* __restrict__ gacc,
                       int nb, int b0)
{
    __shared__ unsigned short tile[2][128][128];   // 65536 B
    __shared__ float2 Wsh[64];
    __shared__ float accn[NSHELL], accp[NSHELL], accq[NSHELL];
    int tid = threadIdx.x, lane = tid & 63, wave = tid >> 6;
    int bi = blockIdx.x;
    int kx = bi % NKX, b = bi / NKX;
    build_W(Wsh, tid);
    if (tid >= 64 && tid < 64 + NSHELL) {
        int s0 = tid - 64;
        accn[s0] = 0.0f; accp[s0] = 0.0f; accq[s0] = 0.0f;
    }
    __syncthreads();
    TwE w = make_twe(Wsh, lane);

    // Phase A: 256 y-FFT lines (vol, z); wave handles 16, processed in pairs
    // (adjacent z, same vol: pair never straddles the idx=128 vol boundary).
    int nv = nb * NKX;
    for (int c = 0; c < 16; c += 2) {
        int idx0 = wave * 16 + c;
        int vol = idx0 >> 7, z0 = idx0 & 127, z1 = z0 + 1;
        const unsigned int* p0 = wsv + ((size_t)vol * nv + (size_t)b * NKX + kx) * PLANE + (size_t)z0 * N;
        const unsigned int* p1 = p0 + N;
        float2 a0 = unpack_bf2(p0[lane]);
        float2 a1 = unpack_bf2(p0[lane + 64]);
        float2 c0 = unpack_bf2(p1[lane]);
        float2 c1 = unpack_bf2(p1[lane + 64]);
        fft128x2(a0, a1, c0, c1, w, lane);
        int ky0 = 2 * rev6(lane);                // a1/c1 hold ky0+1
        tile[vol][ky0][(z0 + ky0) & 127]         = pack_f8(a0);
        tile[vol][ky0 + 1][(z0 + ky0 + 1) & 127] = pack_f8(a1);
        tile[vol][ky0][(z1 + ky0) & 127]         = pack_f8(c0);
        tile[vol][ky0 + 1][(z1 + ky0 + 1) & 127] = pack_f8(c1);
    }
    __syncthreads();

    // Phase B: z-FFT per live ky line (o and t interleaved) + accumulate
    int kx2 = kx * kx;
    int kz0 = 2 * rev6(lane), kz1 = kz0 + 1;
    int cz0 = (kz0 < 64) ? kz0 : kz0 - 128;
    int cz1 = (kz1 < 64) ? kz1 : kz1 - 128;
    int z20 = cz0 * cz0, z21 = cz1 * cz1;

    for (int c = 0; c < 8; c++) {
        int ky = wave + 16 * c;
        int cy = (ky < 64) ? ky : ky - 128;
        int base2 = kx2 + cy * cy;
        if (base2 > 4224) continue;              // whole z-line outside sphere
        int c0 = (lane + ky) & 127;
        int c1 = (lane + 64 + ky) & 127;
        float2 o0 = unpack_f8(tile[0][ky][c0]);
        float2 o1 = unpack_f8(tile[0][ky][c1]);
        float2 t0 = unpack_f8(tile[1][ky][c0]);
        float2 t1 = unpack_f8(tile[1][ky][c1]);
        fft128x2(o0, o1, t0, t1, w, lane);
        int r20 = base2 + z20;
        if (r20 <= 4224) {
            int sh = (int)sqrtf((float)r20);
            if ((sh + 1) * (sh + 1) <= r20) sh++;
            else if (sh * sh > r20) sh--;
            atomicAdd(&accn[sh], o0.x * t0.x + o0.y * t0.y);
            atomicAdd(&accp[sh], o0.x * o0.x + o0.y * o0.y);
            atomicAdd(&accq[sh], t0.x * t0.x + t0.y * t0.y);
        }
        int r21 = base2 + z21;
        if (r21 <= 4224) {
            int sh = (int)sqrtf((float)r21);
            if ((sh + 1) * (sh + 1) <= r21) sh++;
            else if (sh * sh > r21) sh--;
            atomicAdd(&accn[sh], o1.x * t1.x + o1.y * t1.y);
            atomicAdd(&accp[sh], o1.x * o1.x + o1.y * o1.y);
            atomicAdd(&accq[sh], t1.x * t1.x + t1.y * t1.y);
        }
    }
    __syncthreads();

    if (tid < NSHELL) {
        // Hermitian mirror weight * 1/256 (undo the ×16 amplitude pre-scale)
        float wgt = ((kx == 0 || kx == 64) ? 1.0f : 2.0f) * (1.0f / 256.0f);
        float* g = gacc + (size_t)(b0 + b) * ACC_STRIDE;
        atomicAdd(&g[tid],              wgt * accn[tid]);
        atomicAdd(&g[NSHELL + tid],     wgt * accp[tid]);
        atomicAdd(&g[2 * NSHELL + tid], wgt * accq[tid]);
    }
}

// ---------------- Finalize: fsc -> loss scalar -----------------------------
__global__ void finalize_kernel(const float* __restrict__ gacc,
                                float* __restrict__ out)
{
    int lane = threadIdx.x;   // 64 threads, shell = lane+1 (1..64)
    int sh = lane + 1;
    float total = 0.0f;
    #pragma unroll
    for (int b = 0; b < 8; b++) {
        const float* g = gacc + b * ACC_STRIDE;
        float num = g[sh];
        float po  = g[NSHELL + sh];
        float pt  = g[2 * NSHELL + sh];
        float fsc = num / sqrtf(po * pt + 1e-6f);
        fsc = fminf(1.0f, fmaxf(-1.0f, fsc));
        total += fsc;
    }
    #pragma unroll
    for (int off = 32; off; off >>= 1) total += __shfl_down(total, off);
    if (lane == 0) out[0] = 1.0f - total / (64.0f * 8.0f);
}

extern "C" void kernel_launch(void* const* d_in, const int* in_sizes, int n_in,
                              void* d_out, int out_size, void* d_ws, size_t ws_size,
                              hipStream_t stream) {
    const float* in0 = (const float*)d_in[0];   // model_output (8,1,128,128,128)
    const float* in1 = (const float*)d_in[1];   // target
    float* gacc = (float*)d_ws;                 // 8*195 floats
    unsigned int* wsA = (unsigned int*)((char*)d_ws + 8192);

    hipMemsetAsync(d_ws, 0, 8 * ACC_STRIDE * sizeof(float), stream);

    size_t avail = (ws_size > 8192) ? ws_size - 8192 : 0;
    size_t per_batch = 2ull * NKX * PLANE * sizeof(unsigned int);   // ~8.5 MB
    int NB = (int)(avail / per_batch);
    if (NB > 8) NB = 8;
    if (NB < 1) NB = 1;

    // 16 / sqrt(128^3): ortho norm plus ×16 amplitude pre-scale so the fp8
    // LDS plane sits in e4m3's sweet spot; shell sums are ×256, undone at flush.
    const float scale = 1.1048543456039804e-2f;

    for (int b0 = 0; b0 < 8; b0 += NB) {
        int nb = (8 - b0 < NB) ? (8 - b0) : NB;
        size_t plane_cnt = (size_t)nb * NKX * PLANE;
        unsigned int* wso = wsA;                 // [vol][b][kx][z][y] bf16x2
        unsigned int* wst = wsA + plane_cnt;
        fft_x_pack_kernel<<<dim3(nb * 1024), dim3(256), 0, stream>>>(in0, in1, wso, wst, b0, scale);
        fft_yz_acc_kernel<<<dim3(nb * NKX), dim3(1024), 0, stream>>>(wsA, gacc, nb, b0);
    }
    finalize_kernel<<<dim3(1), dim3(64), 0, stream>>>(gacc, (float*)d_out);
}

// Round 7
// 296.542 us; speedup vs baseline: 2.3352x; 1.1036x over previous
//
#include <hip/hip_runtime.h>
#include <math.h>

#define N 128
#define VOL (N*N*N)            // 2097152
#define PLANE (N*N)            // 16384
#define NKX 65                 // kept x-frequencies 0..64 (Hermitian half)
#define NSHELL 65              // shells 0..64
#define ACC_STRIDE 195         // 3*65 per batch

__device__ __forceinline__ int rev6(int x) { return (int)(__brev((unsigned)x) >> 26); }

__device__ __forceinline__ float2 cmul(float2 a, float2 b) {
    return make_float2(a.x * b.x - a.y * b.y, a.x * b.y + a.y * b.x);
}

// Packed-bf16 lane exchange: complex -> one b32 word -> single shuffle.
// v_perm_b32 packs {hi16(y), hi16(x)}; local operand stays fp32.
__device__ __forceinline__ float2 shflx16(float2 v, int m) {
    unsigned p = __builtin_amdgcn_perm(__float_as_uint(v.y), __float_as_uint(v.x), 0x07060302u);
    unsigned q = (unsigned)__shfl_xor((int)p, m);
    return make_float2(__uint_as_float(q << 16), __uint_as_float(q & 0xFFFF0000u));
}

// bf16x2 pack (RNE) / unpack: complex value in one uint (re low, im high)
__device__ __forceinline__ unsigned int pack_bf2(float2 v) {
    unsigned int r = __float_as_uint(v.x);
    unsigned int i = __float_as_uint(v.y);
    r = (r + 0x7FFFu + ((r >> 16) & 1u)) >> 16;
    i = (i + 0x7FFFu + ((i >> 16) & 1u)) & 0xFFFF0000u;
    return i | r;
}
__device__ __forceinline__ float2 unpack_bf2(unsigned int u) {
    return make_float2(__uint_as_float(u << 16), __uint_as_float(u & 0xFFFF0000u));
}

// fp8 e4m3 packed complex (re byte0, im byte1) for the in-LDS plane
__device__ __forceinline__ unsigned short pack_f8(float2 v) {
    int p = __builtin_amdgcn_cvt_pk_fp8_f32(v.x, v.y, 0, false);
    return (unsigned short)(p & 0xFFFF);
}
__device__ __forceinline__ float2 unpack_f8(unsigned short u) {
    auto r = __builtin_amdgcn_cvt_pk_f32_fp8((int)u, false);
    return make_float2(r[0], r[1]);
}

// 64-entry twiddle table W[m] = e^{-2*pi*i*m/128}, built once per block
__device__ __forceinline__ void build_W(float2* Wsh, int tid) {
    if (tid < 64) {
        float s, c;
        sincosf(-6.283185307179586f * (float)tid / 128.0f, &s, &c);
        Wsh[tid] = make_float2(c, s);
    }
}

// Per-lane effective twiddles: w128 for the register stage; we[i] is the
// stage twiddle for high lanes and (1,0) for low lanes (branchless butterfly).
struct TwE { float2 w128; float2 we[5]; };

__device__ __forceinline__ TwE make_twe(const float2* Wsh, int lane) {
    TwE w;
    w.w128 = Wsh[lane];
    #pragma unroll
    for (int i = 0; i < 5; i++) {
        int h = 32 >> i;
        float2 t = Wsh[(lane & (h - 1)) << (i + 1)];
        w.we[i] = (lane & h) ? t : make_float2(1.0f, 0.0f);
    }
    return w;
}

__device__ __forceinline__ void bstage(float2& v, float2 o, float s, float2 we) {
    float tx = fmaf(s, v.x, o.x);
    float ty = fmaf(s, v.y, o.y);
    v = make_float2(tx * we.x - ty * we.y, tx * we.y + ty * we.x);
}

// Two independent 128-pt DIF FFTs, interleaved stage-by-stage; each exchanged
// complex travels as ONE packed-bf16 b32 shuffle (halves LDS-pipe ops).
// Pair A: lane holds a0=x[lane], a1=x[lane+64]; same for pair B.
// Output: a0 = X[2*rev6(lane)], a1 = X[2*rev6(lane)+1].
__device__ __forceinline__ void fft128x2(float2& a0, float2& a1,
                                         float2& b0, float2& b1,
                                         const TwE& w, int lane) {
    float2 d;
    d  = make_float2(a0.x - a1.x, a0.y - a1.y);
    a0 = make_float2(a0.x + a1.x, a0.y + a1.y);
    a1 = cmul(d, w.w128);
    d  = make_float2(b0.x - b1.x, b0.y - b1.y);
    b0 = make_float2(b0.x + b1.x, b0.y + b1.y);
    b1 = cmul(d, w.w128);
    #pragma unroll
    for (int i = 0; i < 5; i++) {
        int h = 32 >> i;
        float s = (lane & h) ? -1.0f : 1.0f;
        float2 oa0 = shflx16(a0, h);
        float2 oa1 = shflx16(a1, h);
        float2 ob0 = shflx16(b0, h);
        float2 ob1 = shflx16(b1, h);
        bstage(a0, oa0, s, w.we[i]);
        bstage(a1, oa1, s, w.we[i]);
        bstage(b0, ob0, s, w.we[i]);
        bstage(b1, ob1, s, w.we[i]);
    }
    float s = (lane & 1) ? -1.0f : 1.0f;
    float2 oa0 = shflx16(a0, 1);
    float2 oa1 = shflx16(a1, 1);
    float2 ob0 = shflx16(b0, 1);
    float2 ob1 = shflx16(b1, 1);
    a0 = make_float2(fmaf(s, a0.x, oa0.x), fmaf(s, a0.y, oa0.y));
    a1 = make_float2(fmaf(s, a1.x, oa1.x), fmaf(s, a1.y, oa1.y));
    b0 = make_float2(fmaf(s, b0.x, ob0.x), fmaf(s, b0.y, ob0.y));
    b1 = make_float2(fmaf(s, b1.x, ob1.x), fmaf(s, b1.y, ob1.y));
}

// slot index holding frequency k after fft128
__device__ __forceinline__ int slot_of(int k) {
    return (k & 1) ? 64 + rev6(k >> 1) : rev6(k >> 1);
}

// ---- Pass 1: packed x-FFT (L = mo + i*tg), Hermitian unpack, keep kx=0..64 ----
// grid: nb*128(z)*8(ytile) blocks of 256. Output (bf16x2): [vol][b][kx][z][y].
__global__ __launch_bounds__(256, 8)
void fft_x_pack_kernel(const float* __restrict__ in0, const float* __restrict__ in1,
                       unsigned int* __restrict__ wso, unsigned int* __restrict__ wst,
                       int b0, float scale)
{
    __shared__ float2 tile[16][129];
    __shared__ float2 Wsh[64];
    int tid = threadIdx.x, lane = tid & 63, wave = tid >> 6;
    int bi = blockIdx.x;
    int yt = bi & 7, z = (bi >> 3) & 127, b = bi >> 10;
    build_W(Wsh, tid);
    __syncthreads();
    TwE w = make_twe(Wsh, lane);

    size_t src_base = (size_t)(b0 + b) * VOL + (size_t)z * PLANE;
    #pragma unroll
    for (int c = 0; c < 4; c += 2) {
        int j0 = wave * 4 + c, j1 = j0 + 1;
        const float* pa0 = in0 + src_base + (size_t)(yt * 16 + j0) * N;
        const float* pa1 = in1 + src_base + (size_t)(yt * 16 + j0) * N;
        const float* pb0 = in0 + src_base + (size_t)(yt * 16 + j1) * N;
        const float* pb1 = in1 + src_base + (size_t)(yt * 16 + j1) * N;
        float2 a0 = make_float2(pa0[lane]      * scale, pa1[lane]      * scale);
        float2 a1 = make_float2(pa0[lane + 64] * scale, pa1[lane + 64] * scale);
        float2 c0 = make_float2(pb0[lane]      * scale, pb1[lane]      * scale);
        float2 c1 = make_float2(pb0[lane + 64] * scale, pb1[lane + 64] * scale);
        fft128x2(a0, a1, c0, c1, w, lane);
        tile[j0][lane]      = a0;
        tile[j0][lane + 64] = a1;
        tile[j1][lane]      = c0;
        tile[j1][lane + 64] = c1;
    }
    __syncthreads();

    // unpack: O = (L(k)+conj(L(-k)))/2 ; T = (L(k)-conj(L(-k)))/(2i)
    size_t dst_off = (size_t)b * NKX * PLANE + (size_t)z * N + yt * 16;
    for (int idx = tid; idx < 2 * NKX * 16; idx += 256) {
        int j   = idx & 15;
        int c   = idx >> 4;              // 0..129
        int vol = (c >= NKX);
        int kx  = c - vol * NKX;
        int mk  = (128 - kx) & 127;
        float2 a  = tile[j][slot_of(kx)];
        float2 bm = tile[j][slot_of(mk)];
        float2 v = vol ? make_float2(0.5f * (a.y + bm.y), 0.5f * (bm.x - a.x))
                       : make_float2(0.5f * (a.x + bm.x), 0.5f * (a.y - bm.y));
        unsigned int* dst = vol ? wst : wso;
        dst[dst_off + (size_t)kx * PLANE + j] = pack_bf2(v);
    }
}

// ---- Fused pass 2: y-FFT + z-FFT + shell accumulation per (b, kx) plane ----
// grid: nb*65 blocks of 1024 (16 waves). LDS plane as fp8x2 (values ×16 from
// pass1's scale; all three shell sums scale by exactly 256, undone at flush).
// Swizzle col = (z + ky) & 127: Phase-A writes 2-way (free), Phase-B reads
// consecutive (free).
__global__ __launch_bounds__(1024, 8)
void fft_yz_acc_kernel(const unsigned int* __restrict__ wsv, float* __restrict__ gacc,
                       int nb, int b0)
{
    __shared__ unsigned short tile[2][128][128];   // 65536 B
    __shared__ float2 Wsh[64];
    __shared__ float accn[NSHELL], accp[NSHELL], accq[NSHELL];
    int tid = threadIdx.x, lane = tid & 63, wave = tid >> 6;
    int bi = blockIdx.x;
    int kx = bi % NKX, b = bi / NKX;
    build_W(Wsh, tid);
    if (tid >= 64 && tid < 64 + NSHELL) {
        int s0 = tid - 64;
        accn[s0] = 0.0f; accp[s0] = 0.0f; accq[s0] = 0.0f;
    }
    __syncthreads();
    TwE w = make_twe(Wsh, lane);

    // Phase A: 256 y-FFT lines (vol, z); wave handles 16, processed in pairs
    // (adjacent z, same vol: pair never straddles the idx=128 vol boundary).
    int nv = nb * NKX;
    for (int c = 0; c < 16; c += 2) {
        int idx0 = wave * 16 + c;
        int vol = idx0 >> 7, z0 = idx0 & 127, z1 = z0 + 1;
        const unsigned int* p0 = wsv + ((size_t)vol * nv + (size_t)b * NKX + kx) * PLANE + (size_t)z0 * N;
        const unsigned int* p1 = p0 + N;
        float2 a0 = unpack_bf2(p0[lane]);
        float2 a1 = unpack_bf2(p0[lane + 64]);
        float2 c0 = unpack_bf2(p1[lane]);
        float2 c1 = unpack_bf2(p1[lane + 64]);
        fft128x2(a0, a1, c0, c1, w, lane);
        int ky0 = 2 * rev6(lane);                // a1/c1 hold ky0+1
        tile[vol][ky0][(z0 + ky0) & 127]         = pack_f8(a0);
        tile[vol][ky0 + 1][(z0 + ky0 + 1) & 127] = pack_f8(a1);
        tile[vol][ky0][(z1 + ky0) & 127]         = pack_f8(c0);
        tile[vol][ky0 + 1][(z1 + ky0 + 1) & 127] = pack_f8(c1);
    }
    __syncthreads();

    // Phase B: z-FFT per live ky line (o and t interleaved) + accumulate
    int kx2 = kx * kx;
    int kz0 = 2 * rev6(lane), kz1 = kz0 + 1;
    int cz0 = (kz0 < 64) ? kz0 : kz0 - 128;
    int cz1 = (kz1 < 64) ? kz1 : kz1 - 128;
    int z20 = cz0 * cz0, z21 = cz1 * cz1;

    for (int c = 0; c < 8; c++) {
        int ky = wave + 16 * c;
        int cy = (ky < 64) ? ky : ky - 128;
        int base2 = kx2 + cy * cy;
        if (base2 > 4224) continue;              // whole z-line outside sphere
        int c0 = (lane + ky) & 127;
        int c1 = (lane + 64 + ky) & 127;
        float2 o0 = unpack_f8(tile[0][ky][c0]);
        float2 o1 = unpack_f8(tile[0][ky][c1]);
        float2 t0 = unpack_f8(tile[1][ky][c0]);
        float2 t1 = unpack_f8(tile[1][ky][c1]);
        fft128x2(o0, o1, t0, t1, w, lane);
        int r20 = base2 + z20;
        if (r20 <= 4224) {
            int sh = (int)sqrtf((float)r20);
            if ((sh + 1) * (sh + 1) <= r20) sh++;
            else if (sh * sh > r20) sh--;
            atomicAdd(&accn[sh], o0.x * t0.x + o0.y * t0.y);
            atomicAdd(&accp[sh], o0.x * o0.x + o0.y * o0.y);
            atomicAdd(&accq[sh], t0.x * t0.x + t0.y * t0.y);
        }
        int r21 = base2 + z21;
        if (r21 <= 4224) {
            int sh = (int)sqrtf((float)r21);
            if ((sh + 1) * (sh + 1) <= r21) sh++;
            else if (sh * sh > r21) sh--;
            atomicAdd(&accn[sh], o1.x * t1.x + o1.y * t1.y);
            atomicAdd(&accp[sh], o1.x * o1.x + o1.y * o1.y);
            atomicAdd(&accq[sh], t1.x * t1.x + t1.y * t1.y);
        }
    }
    __syncthreads();

    if (tid < NSHELL) {
        // Hermitian mirror weight * 1/256 (undo the ×16 amplitude pre-scale)
        float wgt = ((kx == 0 || kx == 64) ? 1.0f : 2.0f) * (1.0f / 256.0f);
        float* g = gacc + (size_t)(b0 + b) * ACC_STRIDE;
        atomicAdd(&g[tid],              wgt * accn[tid]);
        atomicAdd(&g[NSHELL + tid],     wgt * accp[tid]);
        atomicAdd(&g[2 * NSHELL + tid], wgt * accq[tid]);
    }
}

// ---------------- Finalize: fsc -> loss scalar -----------------------------
__global__ void finalize_kernel(const float* __restrict__ gacc,
                                float* __restrict__ out)
{
    int lane = threadIdx.x;   // 64 threads, shell = lane+1 (1..64)
    int sh = lane + 1;
    float total = 0.0f;
    #pragma unroll
    for (int b = 0; b < 8; b++) {
        const float* g = gacc + b * ACC_STRIDE;
        float num = g[sh];
        float po  = g[NSHELL + sh];
        float pt  = g[2 * NSHELL + sh];
        float fsc = num / sqrtf(po * pt + 1e-6f);
        fsc = fminf(1.0f, fmaxf(-1.0f, fsc));
        total += fsc;
    }
    #pragma unroll
    for (int off = 32; off; off >>= 1) total += __shfl_down(total, off);
    if (lane == 0) out[0] = 1.0f - total / (64.0f * 8.0f);
}

extern "C" void kernel_launch(void* const* d_in, const int* in_sizes, int n_in,
                              void* d_out, int out_size, void* d_ws, size_t ws_size,
                              hipStream_t stream) {
    const float* in0 = (const float*)d_in[0];   // model_output (8,1,128,128,128)
    const float* in1 = (const float*)d_in[1];   // target
    float* gacc = (float*)d_ws;                 // 8*195 floats
    unsigned int* wsA = (unsigned int*)((char*)d_ws + 8192);

    hipMemsetAsync(d_ws, 0, 8 * ACC_STRIDE * sizeof(float), stream);

    size_t avail = (ws_size > 8192) ? ws_size - 8192 : 0;
    size_t per_batch = 2ull * NKX * PLANE * sizeof(unsigned int);   // ~8.5 MB
    int NB = (int)(avail / per_batch);
    if (NB > 8) NB = 8;
    if (NB < 1) NB = 1;

    // 16 / sqrt(128^3): ortho norm plus ×16 amplitude pre-scale so the fp8
    // LDS plane sits in e4m3's sweet spot; shell sums are ×256, undone at flush.
    const float scale = 1.1048543456039804e-2f;

    for (int b0 = 0; b0 < 8; b0 += NB) {
        int nb = (8 - b0 < NB) ? (8 - b0) : NB;
        size_t plane_cnt = (size_t)nb * NKX * PLANE;
        unsigned int* wso = wsA;                 // [vol][b][kx][z][y] bf16x2
        unsigned int* wst = wsA + plane_cnt;
        fft_x_pack_kernel<<<dim3(nb * 1024), dim3(256), 0, stream>>>(in0, in1, wso, wst, b0, scale);
        fft_yz_acc_kernel<<<dim3(nb * NKX), dim3(1024), 0, stream>>>(wsA, gacc, nb, b0);
    }
    finalize_kernel<<<dim3(1), dim3(64), 0, stream>>>(gacc, (float*)d_out);
}